// Round 12
// baseline (157.137 us; speedup 1.0000x reference)
//
#include <hip/hip_runtime.h>
#include <hip/hip_bf16.h>

// ---------------- problem constants ----------------
constexpr int kH = 1024, kS = 1024, kNH = 16, kI = 4096, kNOUT = 2560;
constexpr int kQKVN = 1536;  // Q(1024)|K(256)|V(256)

typedef __attribute__((ext_vector_type(8))) short short8v;
typedef __attribute__((ext_vector_type(4))) float f32x4;
typedef unsigned short u16;

#define MFMA16 __builtin_amdgcn_mfma_f32_16x16x32_bf16

__device__ __forceinline__ u16 f2bf(float f) {
  unsigned u = __float_as_uint(f);
  return (u16)((u + 0x7fffu + ((u >> 16) & 1u)) >> 16);
}
__device__ __forceinline__ float bf2f(u16 u) {
  return __uint_as_float(((unsigned)u) << 16);
}
// packed f32x2 -> bf16x2 via HW cvt (RNE, same bits as f2bf)
__device__ __forceinline__ unsigned cvt2bf(float lo, float hi) {
  unsigned r;
  asm("v_cvt_pk_bf16_f32 %0, %1, %2" : "=v"(r) : "v"(lo), "v"(hi));
  return r;
}
__device__ __forceinline__ void gload16(void* lds, const void* g) {
  __builtin_amdgcn_global_load_lds(
      (const __attribute__((address_space(1))) unsigned int*)g,
      (__attribute__((address_space(3))) unsigned int*)lds, 16, 0, 0);
}

// ---------------- workspace layout (float offsets) ----------------
// ints: [1..3] sel, [4..9] gate, [10..15] act, [16..17] hzb, [20..22] counters
constexpr long OFF_H    = 0;                        // 2048x1024 f32
constexpr long OFF_HMP  = OFF_H + 2097152;          // hmean partials [8][2048]
constexpr long OFF_INT  = OFF_HMP + 16384;
constexpr long OFF_GV   = OFF_INT + 64;             // gv[3][1024] (physical layers)
constexpr long OFF_HBF  = OFF_GV + 3072;            // 2048x1024 bf16
constexpr long OFF_QKV  = OFF_HBF + 1048576;        // 2048x1536 bf16
constexpr long OFF_ATT  = OFF_QKV + 1572864;        // 2048x1024 bf16
constexpr long OFF_OBF  = OFF_ATT + 1048576;        // 2048x1024 bf16
constexpr long OFF_PBF  = OFF_OBF + 1048576;        // 2048x4096 bf16

// ---------------- embed (per-block is_common) + gatevec + control-int reset ----------
// blocks [0,2048): embed row; [2048,2240): gv 16-col slice; 2240: zero ip[0..31].
__global__ void embed_gv_kernel(const int* __restrict__ ids, const float* __restrict__ emb,
                                const float* __restrict__ semb, const float* __restrict__ Wq,
                                const float* __restrict__ Wbs, float* __restrict__ h,
                                u16* __restrict__ hbf, float* __restrict__ gv,
                                int* __restrict__ ip) {
  int bid = blockIdx.x, tid = threadIdx.x;
  if (bid < 2048) {
    __shared__ int oks;
    if (tid == 0) oks = 1;
    __syncthreads();
    int ok = 1;
    for (int i = tid; i < 2048; i += 256) ok &= (ids[i] < 1000) ? 1 : 0;
    if (!ok) atomicAnd(&oks, 0);
    __syncthreads();
    int common = oks;
    long row = bid;
    int id = ids[row];
    int cid = id < 0 ? 0 : (id > 999 ? 999 : id);
    const float4* s4 = (const float4*)(common ? semb + (long)cid * kH : emb + (long)id * kH);
    float4 v = s4[tid];
    *((float4*)(h + row * kH) + tid) = v;
    ushort4 u;
    u.x = f2bf(v.x); u.y = f2bf(v.y); u.z = f2bf(v.z); u.w = f2bf(v.w);
    *((ushort4*)(hbf + row * kH) + tid) = u;
  } else if (bid < 2240) {
    int q = bid - 2048;                 // 0..191
    int l = q >> 6, j0 = (q & 63) * 16; // physical layer l, 16 output columns
    int jj = tid & 15, cg = tid >> 4;   // 16 c-groups x 16 columns
    const float* wq = Wq + (long)l * 1048576;
    float acc = 0.f;
    for (int c = cg * 64; c < cg * 64 + 64; ++c)
      acc += Wbs[c] * wq[(long)c * kH + j0 + jj];
    __shared__ float red[256];
    red[tid] = acc;
    __syncthreads();
    if (tid < 16) {
      float s = 0.f;
      #pragma unroll
      for (int g = 0; g < 16; ++g) s += red[g * 16 + tid];  // fixed order
      gv[l * 1024 + j0 + tid] = s;
    }
  } else {
    if (tid < 32) ip[tid] = 0;  // sel/gate/act/hzb/counters
  }
}

// ---------------- hmean partials + last-block tail (scores/top-3 + layer gate) -------
// grid (4,2,8) = 64 blocks. Tail reads gv[li] (4KB) -> fast gate dot.
template <int FIRST>
__global__ __launch_bounds__(256) void hmean_fused_kernel(
    const float* __restrict__ h, float* __restrict__ hmp, const float* __restrict__ gv,
    const float* __restrict__ Wls, const float* __restrict__ bls,
    const float* __restrict__ bbs, int* __restrict__ ip, int layer_i,
    int* __restrict__ cnt) {
  int tid = threadIdx.x;
  int c = blockIdx.x * 256 + tid, b = blockIdx.y, z = blockIdx.z;
  float a = 0.f;
  if (!ip[16 + b]) {  // hzb: logical h==0 -> zero partials
    const float* p = h + ((long)b << 20) + ((long)z << 17) + c;
    #pragma unroll 4
    for (int r = 0; r < 128; ++r) a += p[(long)r << 10];
  }
  hmp[z * 2048 + b * 1024 + c] = a;
  __threadfence();
  __syncthreads();
  __shared__ int lastf;
  if (tid == 0) lastf = (atomicAdd(cnt, 1) == 63) ? 1 : 0;
  __syncthreads();
  if (!lastf) return;
  __threadfence();

  float hm0[4], hm1[4];
  #pragma unroll
  for (int u = 0; u < 4; ++u) {
    int j = tid + u * 256;
    float s0 = 0.f, s1 = 0.f;
    #pragma unroll
    for (int z2 = 0; z2 < 8; ++z2) {
      s0 += hmp[z2 * 2048 + j];
      s1 += hmp[z2 * 2048 + 1024 + j];
    }
    hm0[u] = s0; hm1[u] = s1;
  }
  __shared__ float red[3][256];
  __shared__ int sli;
  int li;
  if constexpr (FIRST) {
    float a0 = 0.f, a1 = 0.f, a2 = 0.f;
    #pragma unroll
    for (int u = 0; u < 4; ++u) {
      int j = tid + u * 256;
      a0 += hm0[u] * Wls[j];
      a1 += hm0[u] * Wls[kH + j];
      a2 += hm0[u] * Wls[2 * kH + j];
    }
    red[0][tid] = a0; red[1][tid] = a1; red[2][tid] = a2;
    __syncthreads();
    for (int st = 128; st; st >>= 1) {
      if (tid < st) {
        red[0][tid] += red[0][tid + st];
        red[1][tid] += red[1][tid + st];
        red[2][tid] += red[2][tid + st];
      }
      __syncthreads();
    }
    if (tid == 0) {
      float sc[3] = {red[0][0] * (1.f / kS) + bls[0], red[1][0] * (1.f / kS) + bls[1],
                     red[2][0] * (1.f / kS) + bls[2]};
      int aa = 0;
      if (sc[1] > sc[aa]) aa = 1;
      if (sc[2] > sc[aa]) aa = 2;
      int b2 = -1; float bb = -3.4e38f;
      for (int i = 0; i < 3; ++i)
        if (i != aa && sc[i] > bb) { bb = sc[i]; b2 = i; }
      ip[1] = aa; ip[2] = b2; ip[3] = 3 - aa - b2;
      sli = aa;
    }
    __syncthreads();
    li = sli;
  } else {
    li = ip[1 + layer_i];
  }
  float g0 = 0.f, g1 = 0.f;
  #pragma unroll
  for (int u = 0; u < 4; ++u) {
    int j = tid + u * 256;
    float v = gv[li * 1024 + j];
    g0 += v * hm0[u];
    g1 += v * hm1[u];
  }
  __syncthreads();
  red[0][tid] = g0; red[1][tid] = g1;
  __syncthreads();
  for (int st = 128; st; st >>= 1) {
    if (tid < st) { red[0][tid] += red[0][tid + st]; red[1][tid] += red[1][tid + st]; }
    __syncthreads();
  }
  if (tid == 0) {
    int* g = ip + 4 + 2 * layer_i;
    g[0] = ((red[0][0] * (1.f / kS) + bbs[0]) > 0.f) ? 1 : 0;
    g[1] = ((red[1][0] * (1.f / kS) + bbs[0]) > 0.f) ? 1 : 0;
  }
}

// ---------------- bf16 MFMA GEMM with f32-B convert-on-stage (HW cvt_pk) ----------
// MODE 0: QKV (segmented B, bf16 out; skips when hzb)
// MODE 1: O    (single B, bf16 out)
// MODE 2: GU   (dual B; bf16 out = prod)
// MODE 3: down (single B; f32 C0 + bf16 C1; hzb maintenance)
// MODE 4: final(single B, no li; f32 out; hzb fast path)
// BM=128, BN in {64,128}; 4 waves as 2m x 2n; wave tile 64 x BN/2.
template <int MODE, int BN>
__global__ __launch_bounds__(256) void gemm_bf_kernel(
    const u16* __restrict__ A, const float* __restrict__ Bf0, const float* __restrict__ Bf1,
    const float* __restrict__ Bf2, void* __restrict__ C0, void* __restrict__ C1,
    int N, int K, const int* __restrict__ li_p,
    const int* __restrict__ gate, const int* __restrict__ act,
    int* __restrict__ hzwr, const int* __restrict__ hz) {
  constexpr bool USE_B1 = (MODE == 2);
  constexpr int WN = BN / 2;    // wave n-tile
  constexpr int NF = WN / 16;   // b-frags per wave
  constexpr int BCH = BN / 32;  // B staging chunks per thread
  __shared__ u16 As[128 * 64];
  __shared__ u16 Bs[BN * 64];
  __shared__ u16 Bs1[USE_B1 ? BN * 64 : 8];

  const int m0 = blockIdx.y * 128, n0 = blockIdx.x * BN;
  const int tid = threadIdx.x;
  const int bb = m0 >> 10;

  if (MODE == 4 && hz != nullptr && hz[bb]) {
    int r = tid >> 1, cb = n0 + (tid & 1) * (BN / 2);
    float* c0 = (float*)C0 + (long)(m0 + r) * N + cb;
    float4 z4 = make_float4(0.f, 0.f, 0.f, 0.f);
    #pragma unroll
    for (int j = 0; j < BN / 2; j += 4) *(float4*)(c0 + j) = z4;
    return;
  }
  if (gate != nullptr) {
    int g = gate[bb];
    int ac = (act != nullptr) ? act[bb] : 1;
    if (MODE == 3 && hzwr != nullptr && tid == 0 && blockIdx.x == 0 && (m0 & 1023) == 0) {
      if (g) hzwr[bb] = ac ? 0 : 1;
    }
    if (!g || !ac) return;
    if (MODE == 0 && hz != nullptr && hz[bb]) return;
  }

  long li = (MODE == 4) ? 0 : (long)(*li_p);
  const float* bsrc;
  const float* bsrc1 = nullptr;
  if constexpr (MODE == 0) {
    if (n0 < 1024)      bsrc = Bf0 + li * 1048576 + (long)n0 * kH;
    else if (n0 < 1280) bsrc = Bf1 + li * 262144 + (long)(n0 - 1024) * kH;
    else                bsrc = Bf2 + li * 262144 + (long)(n0 - 1280) * kH;
  } else if constexpr (MODE == 1) {
    bsrc = Bf0 + li * 1048576 + (long)n0 * kH;
  } else if constexpr (MODE == 2) {
    bsrc = Bf0 + li * 4194304 + (long)n0 * kH;
    bsrc1 = Bf1 + li * 4194304 + (long)n0 * kH;
  } else if constexpr (MODE == 3) {
    bsrc = Bf0 + li * 4194304 + (long)n0 * kI;
  } else {
    bsrc = Bf0 + (long)n0 * kH;
  }

  const int wave = tid >> 6, lane = tid & 63;
  const int lr = lane & 15, lg = lane >> 4;
  const int wm = wave >> 1, wn = wave & 1;

  f32x4 acc[4][NF] = {};
  f32x4 acc1[USE_B1 ? 4 : 1][NF] = {};

  for (int k0 = 0; k0 < K; k0 += 64) {
    #pragma unroll
    for (int j = 0; j < 4; ++j) {
      int c = tid + j * 256;
      int r = c >> 3, c8 = c & 7;
      gload16((char*)As + (wave * 64 + j * 256) * 16,
              A + (long)(m0 + r) * K + k0 + ((c8 ^ (r & 7)) * 8));
    }
    #pragma unroll
    for (int j = 0; j < BCH; ++j) {
      int idx = tid + j * 256;
      int r = idx >> 3, c8 = idx & 7;
      const float* p = bsrc + (long)r * K + k0 + c8 * 8;
      float4 v0 = *(const float4*)p;
      float4 v1 = *(const float4*)(p + 4);
      union { short8v s8; unsigned u[4]; } uo;
      uo.u[0] = cvt2bf(v0.x, v0.y);
      uo.u[1] = cvt2bf(v0.z, v0.w);
      uo.u[2] = cvt2bf(v1.x, v1.y);
      uo.u[3] = cvt2bf(v1.z, v1.w);
      *(short8v*)((char*)Bs + ((r * 128 + c8 * 16) ^ ((r & 7) << 4))) = uo.s8;
      if constexpr (USE_B1) {
        const float* p1 = bsrc1 + (long)r * K + k0 + c8 * 8;
        float4 w0 = *(const float4*)p1;
        float4 w1 = *(const float4*)(p1 + 4);
        union { short8v s8; unsigned u[4]; } uo1;
        uo1.u[0] = cvt2bf(w0.x, w0.y);
        uo1.u[1] = cvt2bf(w0.z, w0.w);
        uo1.u[2] = cvt2bf(w1.x, w1.y);
        uo1.u[3] = cvt2bf(w1.z, w1.w);
        *(short8v*)((char*)Bs1 + ((r * 128 + c8 * 16) ^ ((r & 7) << 4))) = uo1.s8;
      }
    }
    __syncthreads();
    #pragma unroll
    for (int kh = 0; kh < 2; ++kh) {
      const int kb = kh * 64 + lg * 16;
      short8v av[4], bv[NF], b1v[USE_B1 ? NF : 1];
      #pragma unroll
      for (int mi = 0; mi < 4; ++mi) {
        int r = wm * 64 + mi * 16 + lr;
        av[mi] = *(const short8v*)((const char*)As + ((r * 128 + kb) ^ ((r & 7) << 4)));
      }
      #pragma unroll
      for (int ni = 0; ni < NF; ++ni) {
        int r = wn * WN + ni * 16 + lr;
        int byte = (r * 128 + kb) ^ ((r & 7) << 4);
        bv[ni] = *(const short8v*)((const char*)Bs + byte);
        if constexpr (USE_B1) b1v[ni] = *(const short8v*)((const char*)Bs1 + byte);
      }
      #pragma unroll
      for (int mi = 0; mi < 4; ++mi)
        #pragma unroll
        for (int ni = 0; ni < NF; ++ni) {
          acc[mi][ni] = MFMA16(av[mi], bv[ni], acc[mi][ni], 0, 0, 0);
          if constexpr (USE_B1)
            acc1[mi][ni] = MFMA16(av[mi], b1v[ni], acc1[mi][ni], 0, 0, 0);
        }
    }
    __syncthreads();
  }
  #pragma unroll
  for (int mi = 0; mi < 4; ++mi)
    #pragma unroll
    for (int ni = 0; ni < NF; ++ni)
      #pragma unroll
      for (int r = 0; r < 4; ++r) {
        long idx = (long)(m0 + wm * 64 + mi * 16 + lg * 4 + r) * N +
                   (n0 + wn * WN + ni * 16 + lr);
        float v = acc[mi][ni][r];
        if constexpr (MODE == 0 || MODE == 1) ((u16*)C0)[idx] = f2bf(v);
        if constexpr (MODE == 2) ((u16*)C0)[idx] = f2bf(v * acc1[mi][ni][r]);
        if constexpr (MODE == 3) { ((float*)C0)[idx] = v; ((u16*)C1)[idx] = f2bf(v); }
        if constexpr (MODE == 4) ((float*)C0)[idx] = v;
      }
}

// ---------------- rowsum(thresholded softmax) + fused attn = rs*V ----------------
// grid (64, 4, 2). Defer-max: pass 1 accumulates unshifted Sexp + tracks pm; only
// if pm > 60 (overflow risk) re-sweep with exact per-row shift. Threshold booleans
// are shift-invariant. Pass 2 skipped block-uniformly when nothing can pass.
__global__ __launch_bounds__(256) void rowsum_kernel(
    const u16* __restrict__ QKV, const int* __restrict__ gate, int* __restrict__ act,
    const int* __restrict__ hz, u16* __restrict__ ATT) {
  int b = blockIdx.z;
  if (!gate[b] || hz[b]) return;
  int kvg = blockIdx.y, qt = blockIdx.x;
  int tid = threadIdx.x;
  int w = tid >> 6, lane = tid & 63, lr = lane & 15, lg = lane >> 4;

  __shared__ float sm[4][64], ss[4][64], st[4][64], srs[64];
  __shared__ int sflags;  // bit0: need pass2, bit1: overflow
  if (tid == 0) sflags = 0;

  long qrow = ((long)b << 10) + qt * 16 + lr;
  short8v qlo[4], qhi[4];
  #pragma unroll
  for (int hh = 0; hh < 4; ++hh) {
    const u16* qp = QKV + qrow * kQKVN + (kvg * 4 + hh) * 64 + lg * 8;
    qlo[hh] = *(const short8v*)qp;
    qhi[hh] = *(const short8v*)(qp + 32);
  }
  const u16* kb0 = QKV + (((long)b << 10) + w * 256 + lr) * kQKVN + 1024 + kvg * 64 + lg * 8;

  // pass 1: unshifted sum + max
  float s[4][4], pm[4][4];
  #pragma unroll
  for (int hh = 0; hh < 4; ++hh)
    #pragma unroll
    for (int i = 0; i < 4; ++i) { s[hh][i] = 0.f; pm[hh][i] = -3e38f; }
  for (int kt = 0; kt < 16; ++kt) {
    const u16* kp = kb0 + (long)kt * 16 * kQKVN;
    short8v klo = *(const short8v*)kp;
    short8v khi = *(const short8v*)(kp + 32);
    #pragma unroll
    for (int hh = 0; hh < 4; ++hh) {
      f32x4 c = {0.f, 0.f, 0.f, 0.f};
      c = MFMA16(qlo[hh], klo, c, 0, 0, 0);
      c = MFMA16(qhi[hh], khi, c, 0, 0, 0);
      #pragma unroll
      for (int i = 0; i < 4; ++i) {
        float x = c[i] * 0.125f;
        s[hh][i] += __expf(x);
        pm[hh][i] = fmaxf(pm[hh][i], x);
      }
    }
  }
  #pragma unroll
  for (int off = 1; off < 16; off <<= 1)
    #pragma unroll
    for (int hh = 0; hh < 4; ++hh)
      #pragma unroll
      for (int i = 0; i < 4; ++i) {
        s[hh][i] += __shfl_xor(s[hh][i], off);
        pm[hh][i] = fmaxf(pm[hh][i], __shfl_xor(pm[hh][i], off));
      }
  if (lr == 0)
    #pragma unroll
    for (int hh = 0; hh < 4; ++hh)
      #pragma unroll
      for (int i = 0; i < 4; ++i) {
        sm[w][hh * 16 + lg * 4 + i] = pm[hh][i];
        ss[w][hh * 16 + lg * 4 + i] = s[hh][i];
      }
  __syncthreads();
  // merged per-row stats (sum over 4 wave-quarters; max over quarters)
  float Mg[4][4], Sg[4][4];
  int myfl = 0;
  #pragma unroll
  for (int hh = 0; hh < 4; ++hh)
    #pragma unroll
    for (int i = 0; i < 4; ++i) {
      int q = hh * 16 + lg * 4 + i;
      float mm = fmaxf(fmaxf(sm[0][q], sm[1][q]), fmaxf(sm[2][q], sm[3][q]));
      float SS = ss[0][q] + ss[1][q] + ss[2][q] + ss[3][q];
      Mg[hh][i] = mm; Sg[hh][i] = SS;
      if (mm > 60.f) myfl |= 2;                      // overflow risk
      if (__expf(mm) > 0.01f * SS) myfl |= 1;        // max element survives
    }
  if (myfl) atomicOr(&sflags, myfl);
  __syncthreads();
  int flags = sflags;

  if (flags & 2) {
    // rare exact path: recompute S with per-row shift Mg
    #pragma unroll
    for (int hh = 0; hh < 4; ++hh)
      #pragma unroll
      for (int i = 0; i < 4; ++i) s[hh][i] = 0.f;
    for (int kt = 0; kt < 16; ++kt) {
      const u16* kp = kb0 + (long)kt * 16 * kQKVN;
      short8v klo = *(const short8v*)kp;
      short8v khi = *(const short8v*)(kp + 32);
      #pragma unroll
      for (int hh = 0; hh < 4; ++hh) {
        f32x4 c = {0.f, 0.f, 0.f, 0.f};
        c = MFMA16(qlo[hh], klo, c, 0, 0, 0);
        c = MFMA16(qhi[hh], khi, c, 0, 0, 0);
        #pragma unroll
        for (int i = 0; i < 4; ++i) s[hh][i] += __expf(c[i] * 0.125f - Mg[hh][i]);
      }
    }
    #pragma unroll
    for (int off = 1; off < 16; off <<= 1)
      #pragma unroll
      for (int hh = 0; hh < 4; ++hh)
        #pragma unroll
        for (int i = 0; i < 4; ++i) s[hh][i] += __shfl_xor(s[hh][i], off);
    if (lr == 0)
      #pragma unroll
      for (int hh = 0; hh < 4; ++hh)
        #pragma unroll
        for (int i = 0; i < 4; ++i) ss[w][hh * 16 + lg * 4 + i] = s[hh][i];
    __syncthreads();
    #pragma unroll
    for (int hh = 0; hh < 4; ++hh)
      #pragma unroll
      for (int i = 0; i < 4; ++i) {
        int q = hh * 16 + lg * 4 + i;
        Sg[hh][i] = ss[0][q] + ss[1][q] + ss[2][q] + ss[3][q];
      }
    __syncthreads();
  }
  float shift = (flags & 2) ? 1.f : 0.f;

  if (flags & 1) {
    float tt[4][4] = {};
    for (int kt = 0; kt < 16; ++kt) {
      const u16* kp = kb0 + (long)kt * 16 * kQKVN;
      short8v klo = *(const short8v*)kp;
      short8v khi = *(const short8v*)(kp + 32);
      #pragma unroll
      for (int hh = 0; hh < 4; ++hh) {
        f32x4 c = {0.f, 0.f, 0.f, 0.f};
        c = MFMA16(qlo[hh], klo, c, 0, 0, 0);
        c = MFMA16(qhi[hh], khi, c, 0, 0, 0);
        #pragma unroll
        for (int i = 0; i < 4; ++i) {
          float e = __expf(c[i] * 0.125f - shift * Mg[hh][i]);
          if (e > 0.01f * Sg[hh][i]) tt[hh][i] += e;
        }
      }
    }
    #pragma unroll
    for (int off = 1; off < 16; off <<= 1)
      #pragma unroll
      for (int hh = 0; hh < 4; ++hh)
        #pragma unroll
        for (int i = 0; i < 4; ++i) tt[hh][i] += __shfl_xor(tt[hh][i], off);
    if (lr == 0)
      #pragma unroll
      for (int hh = 0; hh < 4; ++hh)
        #pragma unroll
        for (int i = 0; i < 4; ++i) st[w][hh * 16 + lg * 4 + i] = tt[hh][i];
  }
  __syncthreads();
  if (tid < 64) {
    int hh = tid >> 4, q = tid & 15;
    int qq = hh * 16 + q;
    float T = (flags & 1) ? (st[0][qq] + st[1][qq] + st[2][qq] + st[3][qq]) : 0.f;
    float SS = ss[0][qq] + ss[1][qq] + ss[2][qq] + ss[3][qq];
    srs[qq] = T / SS;
    if (T > 0.f) atomicOr(act + b, 1);
  }
  __syncthreads();
  int hh = tid >> 6, rr = (tid >> 2) & 15, d0 = (tid & 3) * 16;
  float rv = srs[hh * 16 + rr];
  long row = ((long)b << 10) + qt * 16 + rr;
  const u16* vp = QKV + row * kQKVN + 1280 + kvg * 64 + d0;
  u16* op = ATT + row * kH + (kvg * 4 + hh) * 64 + d0;
  #pragma unroll
  for (int j = 0; j < 16; j += 4) {
    ushort4 v = *(const ushort4*)(vp + j);
    ushort4 o;
    o.x = f2bf(rv * bf2f(v.x)); o.y = f2bf(rv * bf2f(v.y));
    o.z = f2bf(rv * bf2f(v.z)); o.w = f2bf(rv * bf2f(v.w));
    *(ushort4*)(op + j) = o;
  }
}

// ---------------- launch ----------------
extern "C" void kernel_launch(void* const* d_in, const int* in_sizes, int n_in,
                              void* d_out, int out_size, void* d_ws, size_t ws_size,
                              hipStream_t stream) {
  (void)in_sizes; (void)n_in; (void)out_size; (void)ws_size;
  const int*   ids  = (const int*)d_in[0];
  const float* emb  = (const float*)d_in[1];
  const float* semb = (const float*)d_in[2];
  const float* Wq   = (const float*)d_in[3];
  const float* Wk   = (const float*)d_in[4];
  const float* Wv   = (const float*)d_in[5];
  const float* Wo   = (const float*)d_in[6];
  const float* Wg   = (const float*)d_in[7];
  const float* Wu   = (const float*)d_in[8];
  const float* Wd   = (const float*)d_in[9];
  const float* Wls  = (const float*)d_in[10];
  const float* bls  = (const float*)d_in[11];
  const float* Wbs  = (const float*)d_in[12];
  const float* bbs  = (const float*)d_in[13];
  const float* Wout = (const float*)d_in[14];
  float* out = (float*)d_out;
  float* ws  = (float*)d_ws;

  float* h   = ws + OFF_H;
  float* hmp = ws + OFF_HMP;
  int* ip    = (int*)(ws + OFF_INT);
  int* sel   = ip + 1;
  int* gate  = ip + 4;
  int* act   = ip + 10;
  int* hzb   = ip + 16;
  int* cnt   = ip + 20;
  float* gv  = ws + OFF_GV;
  u16* hbf   = (u16*)(ws + OFF_HBF);
  u16* QKV   = (u16*)(ws + OFF_QKV);
  u16* ATT   = (u16*)(ws + OFF_ATT);
  u16* Obf   = (u16*)(ws + OFF_OBF);
  u16* Pbf   = (u16*)(ws + OFF_PBF);

  embed_gv_kernel<<<2241, 256, 0, stream>>>(ids, emb, semb, Wq, Wbs, h, hbf, gv, ip);

  for (int i = 0; i < 3; i++) {
    const int* li = sel + i;
    int* g_i = gate + 2 * i;
    int* a_i = act + 2 * i;

    if (i == 0)
      hmean_fused_kernel<1><<<dim3(4, 2, 8), 256, 0, stream>>>(h, hmp, gv, Wls, bls, bbs,
                                                               ip, 0, cnt + 0);
    else
      hmean_fused_kernel<0><<<dim3(4, 2, 8), 256, 0, stream>>>(h, hmp, gv, Wls, bls, bbs,
                                                               ip, i, cnt + i);
    gemm_bf_kernel<0, 128><<<dim3(kQKVN / 128, 16), 256, 0, stream>>>(
        hbf, Wq, Wk, Wv, QKV, nullptr, kQKVN, kH, li, g_i, nullptr, nullptr, hzb);
    rowsum_kernel<<<dim3(64, 4, 2), 256, 0, stream>>>(QKV, g_i, a_i, hzb, ATT);
    gemm_bf_kernel<1, 128><<<dim3(kH / 128, 16), 256, 0, stream>>>(
        ATT, Wo, nullptr, nullptr, Obf, nullptr, kH, kH, li, g_i, a_i, nullptr, nullptr);
    gemm_bf_kernel<2, 64><<<dim3(kI / 64, 16), 256, 0, stream>>>(
        Obf, Wg, Wu, nullptr, Pbf, nullptr, kI, kH, li, g_i, a_i, nullptr, nullptr);
    gemm_bf_kernel<3, 128><<<dim3(kH / 128, 16), 256, 0, stream>>>(
        Pbf, Wd, nullptr, nullptr, h, hbf, kH, kI, li, g_i, a_i, hzb, nullptr);
  }
  gemm_bf_kernel<4, 128><<<dim3(kNOUT / 128, 16), 256, 0, stream>>>(
      hbf, Wout, nullptr, nullptr, out, nullptr, kNOUT, kH, nullptr, nullptr, nullptr,
      nullptr, hzb);
}

// Round 13
// 137.342 us; speedup vs baseline: 1.1441x; 1.1441x over previous
//
#include <hip/hip_runtime.h>
#include <hip/hip_bf16.h>

// ---------------- problem constants ----------------
constexpr int kH = 1024, kS = 1024, kNH = 16, kI = 4096, kNOUT = 2560;
constexpr int kQKVN = 1536;  // Q(1024)|K(256)|V(256)

typedef __attribute__((ext_vector_type(8))) short short8v;
typedef __attribute__((ext_vector_type(4))) float f32x4;
typedef unsigned short u16;

#define MFMA16 __builtin_amdgcn_mfma_f32_16x16x32_bf16

__device__ __forceinline__ u16 f2bf(float f) {
  unsigned u = __float_as_uint(f);
  return (u16)((u + 0x7fffu + ((u >> 16) & 1u)) >> 16);
}
__device__ __forceinline__ float bf2f(u16 u) {
  return __uint_as_float(((unsigned)u) << 16);
}
// packed f32x2 -> bf16x2 via HW cvt (RNE, same bits as f2bf)
__device__ __forceinline__ unsigned cvt2bf(float lo, float hi) {
  unsigned r;
  asm("v_cvt_pk_bf16_f32 %0, %1, %2" : "=v"(r) : "v"(lo), "v"(hi));
  return r;
}
__device__ __forceinline__ void gload16(void* lds, const void* g) {
  __builtin_amdgcn_global_load_lds(
      (const __attribute__((address_space(1))) unsigned int*)g,
      (__attribute__((address_space(3))) unsigned int*)lds, 16, 0, 0);
}

// ---------------- workspace layout (float offsets) ----------------
// ints: [1..3] sel, [4..9] gate, [10..15] act, [16..17] hzb, [20..22] hmean counters,
//       [24..29] mlp barrier counters (2 per layer)
constexpr long OFF_H    = 0;                        // 2048x1024 f32
constexpr long OFF_HMP  = OFF_H + 2097152;          // hmean partials [8][2048]
constexpr long OFF_INT  = OFF_HMP + 16384;
constexpr long OFF_GV   = OFF_INT + 64;             // gv[3][1024] (physical layers)
constexpr long OFF_HBF  = OFF_GV + 3072;            // 2048x1024 bf16
constexpr long OFF_QKV  = OFF_HBF + 1048576;        // 2048x1536 bf16
constexpr long OFF_ATT  = OFF_QKV + 1572864;        // 2048x1024 bf16
constexpr long OFF_OBF  = OFF_ATT + 1048576;        // 2048x1024 bf16
constexpr long OFF_PBF  = OFF_OBF + 1048576;        // 2048x4096 bf16

// ---------------- embed (per-block is_common) + gatevec + control-int reset ----------
__global__ void embed_gv_kernel(const int* __restrict__ ids, const float* __restrict__ emb,
                                const float* __restrict__ semb, const float* __restrict__ Wq,
                                const float* __restrict__ Wbs, float* __restrict__ h,
                                u16* __restrict__ hbf, float* __restrict__ gv,
                                int* __restrict__ ip) {
  int bid = blockIdx.x, tid = threadIdx.x;
  if (bid < 2048) {
    __shared__ int oks;
    if (tid == 0) oks = 1;
    __syncthreads();
    int ok = 1;
    for (int i = tid; i < 2048; i += 256) ok &= (ids[i] < 1000) ? 1 : 0;
    if (!ok) atomicAnd(&oks, 0);
    __syncthreads();
    int common = oks;
    long row = bid;
    int id = ids[row];
    int cid = id < 0 ? 0 : (id > 999 ? 999 : id);
    const float4* s4 = (const float4*)(common ? semb + (long)cid * kH : emb + (long)id * kH);
    float4 v = s4[tid];
    *((float4*)(h + row * kH) + tid) = v;
    ushort4 u;
    u.x = f2bf(v.x); u.y = f2bf(v.y); u.z = f2bf(v.z); u.w = f2bf(v.w);
    *((ushort4*)(hbf + row * kH) + tid) = u;
  } else if (bid < 2240) {
    int q = bid - 2048;                 // 0..191
    int l = q >> 6, j0 = (q & 63) * 16; // physical layer l, 16 output columns
    int jj = tid & 15, cg = tid >> 4;
    const float* wq = Wq + (long)l * 1048576;
    float acc = 0.f;
    for (int c = cg * 64; c < cg * 64 + 64; ++c)
      acc += Wbs[c] * wq[(long)c * kH + j0 + jj];
    __shared__ float red[256];
    red[tid] = acc;
    __syncthreads();
    if (tid < 16) {
      float s = 0.f;
      #pragma unroll
      for (int g = 0; g < 16; ++g) s += red[g * 16 + tid];  // fixed order
      gv[l * 1024 + j0 + tid] = s;
    }
  } else {
    if (tid < 32) ip[tid] = 0;  // sel/gate/act/hzb/counters/barriers
  }
}

// ---------------- hmean partials + last-block tail (scores/top-3 + layer gate) -------
template <int FIRST>
__global__ __launch_bounds__(256) void hmean_fused_kernel(
    const float* __restrict__ h, float* __restrict__ hmp, const float* __restrict__ gv,
    const float* __restrict__ Wls, const float* __restrict__ bls,
    const float* __restrict__ bbs, int* __restrict__ ip, int layer_i,
    int* __restrict__ cnt) {
  int tid = threadIdx.x;
  int c = blockIdx.x * 256 + tid, b = blockIdx.y, z = blockIdx.z;
  float a = 0.f;
  if (!ip[16 + b]) {  // hzb: logical h==0 -> zero partials
    const float* p = h + ((long)b << 20) + ((long)z << 17) + c;
    #pragma unroll 4
    for (int r = 0; r < 128; ++r) a += p[(long)r << 10];
  }
  hmp[z * 2048 + b * 1024 + c] = a;
  __threadfence();
  __syncthreads();
  __shared__ int lastf;
  if (tid == 0) lastf = (atomicAdd(cnt, 1) == 63) ? 1 : 0;
  __syncthreads();
  if (!lastf) return;
  __threadfence();

  float hm0[4], hm1[4];
  #pragma unroll
  for (int u = 0; u < 4; ++u) {
    int j = tid + u * 256;
    float s0 = 0.f, s1 = 0.f;
    #pragma unroll
    for (int z2 = 0; z2 < 8; ++z2) {
      s0 += hmp[z2 * 2048 + j];
      s1 += hmp[z2 * 2048 + 1024 + j];
    }
    hm0[u] = s0; hm1[u] = s1;
  }
  __shared__ float red[3][256];
  __shared__ int sli;
  int li;
  if constexpr (FIRST) {
    float a0 = 0.f, a1 = 0.f, a2 = 0.f;
    #pragma unroll
    for (int u = 0; u < 4; ++u) {
      int j = tid + u * 256;
      a0 += hm0[u] * Wls[j];
      a1 += hm0[u] * Wls[kH + j];
      a2 += hm0[u] * Wls[2 * kH + j];
    }
    red[0][tid] = a0; red[1][tid] = a1; red[2][tid] = a2;
    __syncthreads();
    for (int st = 128; st; st >>= 1) {
      if (tid < st) {
        red[0][tid] += red[0][tid + st];
        red[1][tid] += red[1][tid + st];
        red[2][tid] += red[2][tid + st];
      }
      __syncthreads();
    }
    if (tid == 0) {
      float sc[3] = {red[0][0] * (1.f / kS) + bls[0], red[1][0] * (1.f / kS) + bls[1],
                     red[2][0] * (1.f / kS) + bls[2]};
      int aa = 0;
      if (sc[1] > sc[aa]) aa = 1;
      if (sc[2] > sc[aa]) aa = 2;
      int b2 = -1; float bb = -3.4e38f;
      for (int i = 0; i < 3; ++i)
        if (i != aa && sc[i] > bb) { bb = sc[i]; b2 = i; }
      ip[1] = aa; ip[2] = b2; ip[3] = 3 - aa - b2;
      sli = aa;
    }
    __syncthreads();
    li = sli;
  } else {
    li = ip[1 + layer_i];
  }
  float g0 = 0.f, g1 = 0.f;
  #pragma unroll
  for (int u = 0; u < 4; ++u) {
    int j = tid + u * 256;
    float v = gv[li * 1024 + j];
    g0 += v * hm0[u];
    g1 += v * hm1[u];
  }
  __syncthreads();
  red[0][tid] = g0; red[1][tid] = g1;
  __syncthreads();
  for (int st = 128; st; st >>= 1) {
    if (tid < st) { red[0][tid] += red[0][tid + st]; red[1][tid] += red[1][tid + st]; }
    __syncthreads();
  }
  if (tid == 0) {
    int* g = ip + 4 + 2 * layer_i;
    g[0] = ((red[0][0] * (1.f / kS) + bbs[0]) > 0.f) ? 1 : 0;
    g[1] = ((red[1][0] * (1.f / kS) + bbs[0]) > 0.f) ? 1 : 0;
  }
}

// ---------------- bf16 MFMA GEMM with f32-B convert-on-stage (BN=64) ----------------
// MODE 0: QKV (segmented B, bf16 out; skips when hzb or gate off)
// MODE 4: final (single B, no li; f32 out; hzb fast path)
template <int MODE>
__global__ __launch_bounds__(256) void gemm_bf_kernel(
    const u16* __restrict__ A, const float* __restrict__ Bf0, const float* __restrict__ Bf1,
    const float* __restrict__ Bf2, void* __restrict__ C0,
    int N, int K, const int* __restrict__ li_p,
    const int* __restrict__ gate, const int* __restrict__ hz) {
  __shared__ u16 As[128 * 64];
  __shared__ u16 Bs[64 * 64];

  const int m0 = blockIdx.y * 128, n0 = blockIdx.x * 64;
  const int tid = threadIdx.x;
  const int bb = m0 >> 10;

  if (MODE == 4 && hz != nullptr && hz[bb]) {
    int r = tid >> 1, cb = n0 + (tid & 1) * 32;
    float* c0 = (float*)C0 + (long)(m0 + r) * N + cb;
    float4 z4 = make_float4(0.f, 0.f, 0.f, 0.f);
    #pragma unroll
    for (int j = 0; j < 32; j += 4) *(float4*)(c0 + j) = z4;
    return;
  }
  if (MODE == 0) {
    if (!gate[bb]) return;
    if (hz != nullptr && hz[bb]) return;
  }

  long li = (MODE == 4) ? 0 : (long)(*li_p);
  const float* bsrc;
  if constexpr (MODE == 0) {
    if (n0 < 1024)      bsrc = Bf0 + li * 1048576 + (long)n0 * kH;
    else if (n0 < 1280) bsrc = Bf1 + li * 262144 + (long)(n0 - 1024) * kH;
    else                bsrc = Bf2 + li * 262144 + (long)(n0 - 1280) * kH;
  } else {
    bsrc = Bf0 + (long)n0 * kH;
  }

  const int wave = tid >> 6, lane = tid & 63;
  const int lr = lane & 15, lg = lane >> 4;
  const int wm = wave >> 1, wn = wave & 1;

  f32x4 acc[4][2] = {};

  const int sr = tid >> 3, sc8 = tid & 7;
  const int sr1 = (tid + 256) >> 3;

  for (int k0 = 0; k0 < K; k0 += 64) {
    #pragma unroll
    for (int j = 0; j < 4; ++j) {
      int c = tid + j * 256;
      int r = c >> 3, c8 = c & 7;
      gload16((char*)As + (wave * 64 + j * 256) * 16,
              A + (long)(m0 + r) * K + k0 + ((c8 ^ (r & 7)) * 8));
    }
    #pragma unroll
    for (int j = 0; j < 2; ++j) {
      int r = j ? sr1 : sr, c8 = sc8;
      const float* p = bsrc + (long)r * K + k0 + c8 * 8;
      float4 v0 = *(const float4*)p;
      float4 v1 = *(const float4*)(p + 4);
      union { short8v s8; unsigned u[4]; } uo;
      uo.u[0] = cvt2bf(v0.x, v0.y);
      uo.u[1] = cvt2bf(v0.z, v0.w);
      uo.u[2] = cvt2bf(v1.x, v1.y);
      uo.u[3] = cvt2bf(v1.z, v1.w);
      *(short8v*)((char*)Bs + ((r * 128 + c8 * 16) ^ ((r & 7) << 4))) = uo.s8;
    }
    __syncthreads();
    #pragma unroll
    for (int kh = 0; kh < 2; ++kh) {
      const int kb = kh * 64 + lg * 16;
      short8v av[4], bv[2];
      #pragma unroll
      for (int mi = 0; mi < 4; ++mi) {
        int r = wm * 64 + mi * 16 + lr;
        av[mi] = *(const short8v*)((const char*)As + ((r * 128 + kb) ^ ((r & 7) << 4)));
      }
      #pragma unroll
      for (int ni = 0; ni < 2; ++ni) {
        int r = wn * 32 + ni * 16 + lr;
        bv[ni] = *(const short8v*)((const char*)Bs + ((r * 128 + kb) ^ ((r & 7) << 4)));
      }
      #pragma unroll
      for (int mi = 0; mi < 4; ++mi)
        #pragma unroll
        for (int ni = 0; ni < 2; ++ni)
          acc[mi][ni] = MFMA16(av[mi], bv[ni], acc[mi][ni], 0, 0, 0);
    }
    __syncthreads();
  }
  #pragma unroll
  for (int mi = 0; mi < 4; ++mi)
    #pragma unroll
    for (int ni = 0; ni < 2; ++ni)
      #pragma unroll
      for (int r = 0; r < 4; ++r) {
        long idx = (long)(m0 + wm * 64 + mi * 16 + lg * 4 + r) * N +
                   (n0 + wn * 32 + ni * 16 + lr);
        float v = acc[mi][ni][r];
        if constexpr (MODE == 0) ((u16*)C0)[idx] = f2bf(v);
        else ((float*)C0)[idx] = v;
      }
}

// ---------------- fused MLP: O -> GU -> down in one node, manual device barrier -------
// grid = 256 blocks (32KB LDS -> 5 blocks/CU capacity -> all resident, no deadlock).
// Empty (1 node instead of 3) when no batch has gate&&act.
__device__ __forceinline__ void dev_barrier(int* cnt, int target) {
  __syncthreads();
  __threadfence();
  if (threadIdx.x == 0) {
    atomicAdd(cnt, 1);
    while (atomicAdd(cnt, 0) < target) __builtin_amdgcn_s_sleep(8);
  }
  __syncthreads();
  __threadfence();
}

// PH 0: O = ATT @ Wo.T (bf16 out). PH 1: P = (O@Wg.T)*(O@Wu.T). PH 2: h = P @ Wd.T.
template <int PH>
__device__ __forceinline__ void mlp_tile(int t, long li, const u16* __restrict__ A,
                                         const float* __restrict__ B0base,
                                         const float* __restrict__ B1base,
                                         void* __restrict__ C0, void* __restrict__ C1,
                                         int ac0, int ac1, u16* As, u16* Bs, u16* Bs1) {
  constexpr bool USE_B1 = (PH == 1);
  constexpr int N = (PH == 1) ? 4096 : 1024;
  constexpr int K = (PH == 2) ? 4096 : 1024;
  const int tid = threadIdx.x;
  const int tm = t & 15, tn = t >> 4;
  const int m0 = tm * 128, n0 = tn * 64;
  if (!((tm >> 3) ? ac1 : ac0)) return;

  const float* bsrc;
  const float* bsrc1 = nullptr;
  if constexpr (PH == 0) {
    bsrc = B0base + li * 1048576 + (long)n0 * 1024;
  } else if constexpr (PH == 1) {
    bsrc = B0base + li * 4194304 + (long)n0 * 1024;
    bsrc1 = B1base + li * 4194304 + (long)n0 * 1024;
  } else {
    bsrc = B0base + li * 4194304 + (long)n0 * 4096;
  }

  const int wave = tid >> 6, lane = tid & 63;
  const int lr = lane & 15, lg = lane >> 4;
  const int wm = wave >> 1, wn = wave & 1;

  f32x4 acc[4][2] = {};
  f32x4 acc1[USE_B1 ? 4 : 1][2] = {};

  const int sr = tid >> 3, sc8 = tid & 7;
  const int sr1 = (tid + 256) >> 3;

  for (int k0 = 0; k0 < K; k0 += 64) {
    #pragma unroll
    for (int j = 0; j < 4; ++j) {
      int c = tid + j * 256;
      int r = c >> 3, c8 = c & 7;
      gload16((char*)As + (wave * 64 + j * 256) * 16,
              A + (long)(m0 + r) * K + k0 + ((c8 ^ (r & 7)) * 8));
    }
    #pragma unroll
    for (int j = 0; j < 2; ++j) {
      int r = j ? sr1 : sr, c8 = sc8;
      const float* p = bsrc + (long)r * K + k0 + c8 * 8;
      float4 v0 = *(const float4*)p;
      float4 v1 = *(const float4*)(p + 4);
      union { short8v s8; unsigned u[4]; } uo;
      uo.u[0] = cvt2bf(v0.x, v0.y);
      uo.u[1] = cvt2bf(v0.z, v0.w);
      uo.u[2] = cvt2bf(v1.x, v1.y);
      uo.u[3] = cvt2bf(v1.z, v1.w);
      *(short8v*)((char*)Bs + ((r * 128 + c8 * 16) ^ ((r & 7) << 4))) = uo.s8;
      if constexpr (USE_B1) {
        const float* p1 = bsrc1 + (long)r * K + k0 + c8 * 8;
        float4 w0 = *(const float4*)p1;
        float4 w1 = *(const float4*)(p1 + 4);
        union { short8v s8; unsigned u[4]; } uo1;
        uo1.u[0] = cvt2bf(w0.x, w0.y);
        uo1.u[1] = cvt2bf(w0.z, w0.w);
        uo1.u[2] = cvt2bf(w1.x, w1.y);
        uo1.u[3] = cvt2bf(w1.z, w1.w);
        *(short8v*)((char*)Bs1 + ((r * 128 + c8 * 16) ^ ((r & 7) << 4))) = uo1.s8;
      }
    }
    __syncthreads();
    #pragma unroll
    for (int kh = 0; kh < 2; ++kh) {
      const int kb = kh * 64 + lg * 16;
      short8v av[4], bv[2], b1v[2];
      #pragma unroll
      for (int mi = 0; mi < 4; ++mi) {
        int r = wm * 64 + mi * 16 + lr;
        av[mi] = *(const short8v*)((const char*)As + ((r * 128 + kb) ^ ((r & 7) << 4)));
      }
      #pragma unroll
      for (int ni = 0; ni < 2; ++ni) {
        int r = wn * 32 + ni * 16 + lr;
        int byte = (r * 128 + kb) ^ ((r & 7) << 4);
        bv[ni] = *(const short8v*)((const char*)Bs + byte);
        if constexpr (USE_B1) b1v[ni] = *(const short8v*)((const char*)Bs1 + byte);
      }
      #pragma unroll
      for (int mi = 0; mi < 4; ++mi)
        #pragma unroll
        for (int ni = 0; ni < 2; ++ni) {
          acc[mi][ni] = MFMA16(av[mi], bv[ni], acc[mi][ni], 0, 0, 0);
          if constexpr (USE_B1)
            acc1[mi][ni] = MFMA16(av[mi], b1v[ni], acc1[mi][ni], 0, 0, 0);
        }
    }
    __syncthreads();
  }
  #pragma unroll
  for (int mi = 0; mi < 4; ++mi)
    #pragma unroll
    for (int ni = 0; ni < 2; ++ni)
      #pragma unroll
      for (int r = 0; r < 4; ++r) {
        long idx = (long)(m0 + wm * 64 + mi * 16 + lg * 4 + r) * N +
                   (n0 + wn * 32 + ni * 16 + lr);
        float v = acc[mi][ni][r];
        if constexpr (PH == 0) ((u16*)C0)[idx] = f2bf(v);
        if constexpr (PH == 1) ((u16*)C0)[idx] = f2bf(v * acc1[mi][ni][r]);
        if constexpr (PH == 2) { ((float*)C0)[idx] = v; ((u16*)C1)[idx] = f2bf(v); }
      }
}

__global__ __launch_bounds__(256) void mlp_kernel(
    const u16* __restrict__ ATT, const float* __restrict__ Wo, const float* __restrict__ Wg,
    const float* __restrict__ Wu, const float* __restrict__ Wd, u16* __restrict__ Obf,
    u16* __restrict__ Pbf, float* __restrict__ h, u16* __restrict__ hbf,
    const int* __restrict__ li_p, const int* __restrict__ gate,
    const int* __restrict__ act, int* __restrict__ hzwr, int* __restrict__ cnt2) {
  const int tid = threadIdx.x, bid = blockIdx.x;
  int g0 = gate[0], g1 = gate[1];
  int a0 = act[0], a1 = act[1];
  if (bid == 0 && tid == 0) {
    if (g0) hzwr[0] = a0 ? 0 : 1;  // new_h==0 exactly when attention all-thresholded
    if (g1) hzwr[1] = a1 ? 0 : 1;
  }
  int ac0 = g0 && a0, ac1 = g1 && a1;
  if (!ac0 && !ac1) return;  // uniform across grid: no barrier participation needed

  __shared__ u16 As[128 * 64];   // 16 KB
  __shared__ u16 Bs[64 * 64];    // 8 KB
  __shared__ u16 Bs1[64 * 64];   // 8 KB
  long li = (long)(*li_p);

  // O = ATT @ Wo.T  (256 tiles, 1/block)
  mlp_tile<0>(bid, li, ATT, Wo, nullptr, Obf, nullptr, ac0, ac1, As, Bs, Bs1);
  dev_barrier(cnt2 + 0, 256);
  // P = (O @ Wg.T) * (O @ Wu.T)  (1024 tiles, 4/block)
  for (int t = bid; t < 1024; t += 256)
    mlp_tile<1>(t, li, Obf, Wg, Wu, Pbf, nullptr, ac0, ac1, As, Bs, Bs1);
  dev_barrier(cnt2 + 1, 256);
  // h = P @ Wd.T  (256 tiles, 1/block)
  mlp_tile<2>(bid, li, Pbf, Wd, nullptr, h, hbf, ac0, ac1, As, Bs, Bs1);
}

// ---------------- rowsum(thresholded softmax) + fused attn = rs*V ----------------
// grid (64, 4, 2). Defer-max: pass 1 accumulates unshifted Sexp + tracks pm; only
// if pm > 60 (overflow risk) re-sweep with exact per-row shift. Threshold booleans
// are shift-invariant. Pass 2 skipped block-uniformly when nothing can pass.
__global__ __launch_bounds__(256) void rowsum_kernel(
    const u16* __restrict__ QKV, const int* __restrict__ gate, int* __restrict__ act,
    const int* __restrict__ hz, u16* __restrict__ ATT) {
  int b = blockIdx.z;
  if (!gate[b] || hz[b]) return;
  int kvg = blockIdx.y, qt = blockIdx.x;
  int tid = threadIdx.x;
  int w = tid >> 6, lane = tid & 63, lr = lane & 15, lg = lane >> 4;

  __shared__ float sm[4][64], ss[4][64], st[4][64], srs[64];
  __shared__ int sflags;  // bit0: need pass2, bit1: overflow
  if (tid == 0) sflags = 0;

  long qrow = ((long)b << 10) + qt * 16 + lr;
  short8v qlo[4], qhi[4];
  #pragma unroll
  for (int hh = 0; hh < 4; ++hh) {
    const u16* qp = QKV + qrow * kQKVN + (kvg * 4 + hh) * 64 + lg * 8;
    qlo[hh] = *(const short8v*)qp;
    qhi[hh] = *(const short8v*)(qp + 32);
  }
  const u16* kb0 = QKV + (((long)b << 10) + w * 256 + lr) * kQKVN + 1024 + kvg * 64 + lg * 8;

  // pass 1: unshifted sum + max
  float s[4][4], pm[4][4];
  #pragma unroll
  for (int hh = 0; hh < 4; ++hh)
    #pragma unroll
    for (int i = 0; i < 4; ++i) { s[hh][i] = 0.f; pm[hh][i] = -3e38f; }
  for (int kt = 0; kt < 16; ++kt) {
    const u16* kp = kb0 + (long)kt * 16 * kQKVN;
    short8v klo = *(const short8v*)kp;
    short8v khi = *(const short8v*)(kp + 32);
    #pragma unroll
    for (int hh = 0; hh < 4; ++hh) {
      f32x4 c = {0.f, 0.f, 0.f, 0.f};
      c = MFMA16(qlo[hh], klo, c, 0, 0, 0);
      c = MFMA16(qhi[hh], khi, c, 0, 0, 0);
      #pragma unroll
      for (int i = 0; i < 4; ++i) {
        float x = c[i] * 0.125f;
        s[hh][i] += __expf(x);
        pm[hh][i] = fmaxf(pm[hh][i], x);
      }
    }
  }
  #pragma unroll
  for (int off = 1; off < 16; off <<= 1)
    #pragma unroll
    for (int hh = 0; hh < 4; ++hh)
      #pragma unroll
      for (int i = 0; i < 4; ++i) {
        s[hh][i] += __shfl_xor(s[hh][i], off);
        pm[hh][i] = fmaxf(pm[hh][i], __shfl_xor(pm[hh][i], off));
      }
  if (lr == 0)
    #pragma unroll
    for (int hh = 0; hh < 4; ++hh)
      #pragma unroll
      for (int i = 0; i < 4; ++i) {
        sm[w][hh * 16 + lg * 4 + i] = pm[hh][i];
        ss[w][hh * 16 + lg * 4 + i] = s[hh][i];
      }
  __syncthreads();
  float Mg[4][4], Sg[4][4];
  int myfl = 0;
  #pragma unroll
  for (int hh = 0; hh < 4; ++hh)
    #pragma unroll
    for (int i = 0; i < 4; ++i) {
      int q = hh * 16 + lg * 4 + i;
      float mm = fmaxf(fmaxf(sm[0][q], sm[1][q]), fmaxf(sm[2][q], sm[3][q]));
      float SS = ss[0][q] + ss[1][q] + ss[2][q] + ss[3][q];
      Mg[hh][i] = mm; Sg[hh][i] = SS;
      if (mm > 60.f) myfl |= 2;
      if (__expf(mm) > 0.01f * SS) myfl |= 1;
    }
  if (myfl) atomicOr(&sflags, myfl);
  __syncthreads();
  int flags = sflags;

  if (flags & 2) {
    #pragma unroll
    for (int hh = 0; hh < 4; ++hh)
      #pragma unroll
      for (int i = 0; i < 4; ++i) s[hh][i] = 0.f;
    for (int kt = 0; kt < 16; ++kt) {
      const u16* kp = kb0 + (long)kt * 16 * kQKVN;
      short8v klo = *(const short8v*)kp;
      short8v khi = *(const short8v*)(kp + 32);
      #pragma unroll
      for (int hh = 0; hh < 4; ++hh) {
        f32x4 c = {0.f, 0.f, 0.f, 0.f};
        c = MFMA16(qlo[hh], klo, c, 0, 0, 0);
        c = MFMA16(qhi[hh], khi, c, 0, 0, 0);
        #pragma unroll
        for (int i = 0; i < 4; ++i) s[hh][i] += __expf(c[i] * 0.125f - Mg[hh][i]);
      }
    }
    #pragma unroll
    for (int off = 1; off < 16; off <<= 1)
      #pragma unroll
      for (int hh = 0; hh < 4; ++hh)
        #pragma unroll
        for (int i = 0; i < 4; ++i) s[hh][i] += __shfl_xor(s[hh][i], off);
    if (lr == 0)
      #pragma unroll
      for (int hh = 0; hh < 4; ++hh)
        #pragma unroll
        for (int i = 0; i < 4; ++i) ss[w][hh * 16 + lg * 4 + i] = s[hh][i];
    __syncthreads();
    #pragma unroll
    for (int hh = 0; hh < 4; ++hh)
      #pragma unroll
      for (int i = 0; i < 4; ++i) {
        int q = hh * 16 + lg * 4 + i;
        Sg[hh][i] = ss[0][q] + ss[1][q] + ss[2][q] + ss[3][q];
      }
    __syncthreads();
  }
  float shift = (flags & 2) ? 1.f : 0.f;

  if (flags & 1) {
    float tt[4][4] = {};
    for (int kt = 0; kt < 16; ++kt) {
      const u16* kp = kb0 + (long)kt * 16 * kQKVN;
      short8v klo = *(const short8v*)kp;
      short8v khi = *(const short8v*)(kp + 32);
      #pragma unroll
      for (int hh = 0; hh < 4; ++hh) {
        f32x4 c = {0.f, 0.f, 0.f, 0.f};
        c = MFMA16(qlo[hh], klo, c, 0, 0, 0);
        c = MFMA16(qhi[hh], khi, c, 0, 0, 0);
        #pragma unroll
        for (int i = 0; i < 4; ++i) {
          float e = __expf(c[i] * 0.125f - shift * Mg[hh][i]);
          if (e > 0.01f * Sg[hh][i]) tt[hh][i] += e;
        }
      }
    }
    #pragma unroll
    for (int off = 1; off < 16; off <<= 1)
      #pragma unroll
      for (int hh = 0; hh < 4; ++hh)
        #pragma unroll
        for (int i = 0; i < 4; ++i) tt[hh][i] += __shfl_xor(tt[hh][i], off);
    if (lr == 0)
      #pragma unroll
      for (int hh = 0; hh < 4; ++hh)
        #pragma unroll
        for (int i = 0; i < 4; ++i) st[w][hh * 16 + lg * 4 + i] = tt[hh][i];
  }
  __syncthreads();
  if (tid < 64) {
    int hh = tid >> 4, q = tid & 15;
    int qq = hh * 16 + q;
    float T = (flags & 1) ? (st[0][qq] + st[1][qq] + st[2][qq] + st[3][qq]) : 0.f;
    float SS = ss[0][qq] + ss[1][qq] + ss[2][qq] + ss[3][qq];
    srs[qq] = T / SS;
    if (T > 0.f) atomicOr(act + b, 1);
  }
  __syncthreads();
  int hh = tid >> 6, rr = (tid >> 2) & 15, d0 = (tid & 3) * 16;
  float rv = srs[hh * 16 + rr];
  long row = ((long)b << 10) + qt * 16 + rr;
  const u16* vp = QKV + row * kQKVN + 1280 + kvg * 64 + d0;
  u16* op = ATT + row * kH + (kvg * 4 + hh) * 64 + d0;
  #pragma unroll
  for (int j = 0; j < 16; j += 4) {
    ushort4 v = *(const ushort4*)(vp + j);
    ushort4 o;
    o.x = f2bf(rv * bf2f(v.x)); o.y = f2bf(rv * bf2f(v.y));
    o.z = f2bf(rv * bf2f(v.z)); o.w = f2bf(rv * bf2f(v.w));
    *(ushort4*)(op + j) = o;
  }
}

// ---------------- launch ----------------
extern "C" void kernel_launch(void* const* d_in, const int* in_sizes, int n_in,
                              void* d_out, int out_size, void* d_ws, size_t ws_size,
                              hipStream_t stream) {
  (void)in_sizes; (void)n_in; (void)out_size; (void)ws_size;
  const int*   ids  = (const int*)d_in[0];
  const float* emb  = (const float*)d_in[1];
  const float* semb = (const float*)d_in[2];
  const float* Wq   = (const float*)d_in[3];
  const float* Wk   = (const float*)d_in[4];
  const float* Wv   = (const float*)d_in[5];
  const float* Wo   = (const float*)d_in[6];
  const float* Wg   = (const float*)d_in[7];
  const float* Wu   = (const float*)d_in[8];
  const float* Wd   = (const float*)d_in[9];
  const float* Wls  = (const float*)d_in[10];
  const float* bls  = (const float*)d_in[11];
  const float* Wbs  = (const float*)d_in[12];
  const float* bbs  = (const float*)d_in[13];
  const float* Wout = (const float*)d_in[14];
  float* out = (float*)d_out;
  float* ws  = (float*)d_ws;

  float* h   = ws + OFF_H;
  float* hmp = ws + OFF_HMP;
  int* ip    = (int*)(ws + OFF_INT);
  int* sel   = ip + 1;
  int* gate  = ip + 4;
  int* act   = ip + 10;
  int* hzb   = ip + 16;
  int* cnt   = ip + 20;
  int* bar   = ip + 24;
  float* gv  = ws + OFF_GV;
  u16* hbf   = (u16*)(ws + OFF_HBF);
  u16* QKV   = (u16*)(ws + OFF_QKV);
  u16* ATT   = (u16*)(ws + OFF_ATT);
  u16* Obf   = (u16*)(ws + OFF_OBF);
  u16* Pbf   = (u16*)(ws + OFF_PBF);

  embed_gv_kernel<<<2241, 256, 0, stream>>>(ids, emb, semb, Wq, Wbs, h, hbf, gv, ip);

  for (int i = 0; i < 3; i++) {
    const int* li = sel + i;
    int* g_i = gate + 2 * i;
    int* a_i = act + 2 * i;

    if (i == 0)
      hmean_fused_kernel<1><<<dim3(4, 2, 8), 256, 0, stream>>>(h, hmp, gv, Wls, bls, bbs,
                                                               ip, 0, cnt + 0);
    else
      hmean_fused_kernel<0><<<dim3(4, 2, 8), 256, 0, stream>>>(h, hmp, gv, Wls, bls, bbs,
                                                               ip, i, cnt + i);
    // QKV = h @ [Wq|Wk|Wv].T
    gemm_bf_kernel<0><<<dim3(kQKVN / 64, 16), 256, 0, stream>>>(
        hbf, Wq, Wk, Wv, QKV, kQKVN, kH, li, g_i, hzb);
    // thresholded-softmax rowsum + attn (sets act)
    rowsum_kernel<<<dim3(64, 4, 2), 256, 0, stream>>>(QKV, g_i, a_i, hzb, ATT);
    // fused O -> GU -> down (1 node; empty unless gate&&act)
    mlp_kernel<<<256, 256, 0, stream>>>(ATT, Wo, Wg, Wu, Wd, Obf, Pbf, h, hbf,
                                        li, g_i, a_i, hzb, bar + 2 * i);
  }
  // out = h @ Wout[:2560].T (per-batch zero fast path when h logically 0)
  gemm_bf_kernel<4><<<dim3(kNOUT / 64, 16), 256, 0, stream>>>(
      hbf, Wout, nullptr, nullptr, out, kNOUT, kH, nullptr, nullptr, hzb);
}